// Round 3
// baseline (1739.985 us; speedup 1.0000x reference)
//
#include <hip/hip_runtime.h>

constexpr int NB   = 4;
constexpr int PER  = 5000;
constexpr int NQ   = 20000;
constexpr int D    = 256;
constexpr int NH   = 8;
constexpr int DH   = 32;
constexpr int KSA  = 1000;
constexpr int STOT = 5440;
constexpr int DFF  = 1024;
constexpr float SCALE = 0.17677669529663687f;  // 1/sqrt(32)

__device__ __forceinline__ float gelu_f(float x) {
    float t = tanhf(0.7978845608028654f * (x + 0.044715f * x * x * x));
    return 0.5f * x * (1.0f + t);
}

// ---------------- top-k (set semantics, tie-break = lower index) ----------------
__global__ __launch_bounds__(1024) void topk_kernel(const float* __restrict__ elec,
                                                    const float* __restrict__ sal,
                                                    int* __restrict__ tk)
{
    __shared__ unsigned int keys[PER];
    __shared__ int scnt;
    const int b = blockIdx.x, tid = threadIdx.x;
    for (int i = tid; i < PER; i += 1024) {
        float sc = elec[b * PER + i] + sal[b * PER + i];
        unsigned u = __float_as_uint(sc);
        keys[i] = (u & 0x80000000u) ? ~u : (u | 0x80000000u);
    }
    __syncthreads();
    unsigned lo = 0u, hi = 0xFFFFFFFFu;
    for (int it = 0; it < 33; ++it) {
        unsigned mid = (unsigned)(((unsigned long long)lo + (unsigned long long)hi + 1ull) >> 1);
        if (mid == lo) break;
        if (tid == 0) scnt = 0;
        __syncthreads();
        int c = 0;
        for (int i = tid; i < PER; i += 1024) c += (keys[i] >= mid) ? 1 : 0;
        if (c) atomicAdd(&scnt, c);
        __syncthreads();
        const int total = scnt;
        __syncthreads();
        if (total >= KSA) lo = mid; else hi = mid - 1u;
    }
    const unsigned T = lo;
    if (tid == 0) scnt = 0;
    __syncthreads();
    for (int i = tid; i < PER; i += 1024) {
        if (keys[i] > T) {
            int pos = atomicAdd(&scnt, 1);
            tk[b * KSA + pos] = b * PER + i;
        }
    }
    __syncthreads();
    if (tid == 0) {
        int c = scnt;
        for (int i = 0; i < PER && c < KSA; ++i)
            if (keys[i] == T) { tk[b * KSA + c] = b * PER + i; ++c; }
    }
}

// ---------------- LayerNorm (one wave per 256-wide row) ----------------
template<bool GATHER>
__global__ __launch_bounds__(256) void ln_kernel(const float* __restrict__ x,
                                                 const float* __restrict__ gw,
                                                 const float* __restrict__ bw,
                                                 float* __restrict__ y, int rows,
                                                 const int* __restrict__ gidx)
{
    const int row  = blockIdx.x * 4 + (threadIdx.x >> 6);
    const int lane = threadIdx.x & 63;
    if (row >= rows) return;
    const int xr = GATHER ? gidx[row] : row;
    const float4 v = *(const float4*)(x + (size_t)xr * D + lane * 4);
    float s = v.x + v.y + v.z + v.w;
    #pragma unroll
    for (int m = 1; m < 64; m <<= 1) s += __shfl_xor(s, m);
    const float mean = s * (1.0f / D);
    const float dx = v.x - mean, dy = v.y - mean, dz = v.z - mean, dw = v.w - mean;
    float ss = dx * dx + dy * dy + dz * dz + dw * dw;
    #pragma unroll
    for (int m = 1; m < 64; m <<= 1) ss += __shfl_xor(ss, m);
    const float rstd = rsqrtf(ss * (1.0f / D) + 1e-5f);
    const float4 g4 = *(const float4*)(gw + lane * 4);
    const float4 b4 = *(const float4*)(bw + lane * 4);
    float4 o;
    o.x = dx * rstd * g4.x + b4.x;
    o.y = dy * rstd * g4.y + b4.y;
    o.z = dz * rstd * g4.z + b4.z;
    o.w = dw * rstd * g4.w + b4.w;
    *(float4*)(y + (size_t)row * D + lane * 4) = o;
}

// ---------------- f32 tiled GEMM: C[M,N] = A[M,K] @ B[K,N] (+epilogue) ----------------
enum { EPI_STORE = 0, EPI_BIAS = 1, EPI_BIAS_GELU = 2, EPI_ADD = 3, EPI_ADD_BIAS = 4, EPI_SCATTER_ADD = 5 };
constexpr int BM = 128, BN = 128, BK = 16, LDSS = 132;

template<int EPI>
__global__ __launch_bounds__(256) void gemm_f32(const float* __restrict__ A,
                                                const float* __restrict__ Bm,
                                                const float* __restrict__ bias,
                                                float* __restrict__ C,
                                                const int* __restrict__ scat,
                                                int M, int Nn, int K)
{
    __shared__ float As[BK * LDSS];   // As[k][m] (transposed)
    __shared__ float Bs[BK * LDSS];   // Bs[k][n]
    const int tid  = threadIdx.x;
    const int row0 = blockIdx.y * BM;
    const int col0 = blockIdx.x * BN;
    const int tx = tid & 15, ty = tid >> 4;

    float c[8][8];
    #pragma unroll
    for (int j = 0; j < 8; ++j)
        #pragma unroll
        for (int i = 0; i < 8; ++i) c[j][i] = 0.f;

    for (int ks = 0; ks < K; ks += BK) {
        #pragma unroll
        for (int i = 0; i < 2; ++i) {           // A: 128x16 = 512 float4
            const int slot = tid + i * 256;
            const int r = slot >> 2, c4 = slot & 3;
            const int gr = row0 + r;
            float4 v = make_float4(0.f, 0.f, 0.f, 0.f);
            if (gr < M) v = *(const float4*)(A + (size_t)gr * K + ks + c4 * 4);
            As[(c4 * 4 + 0) * LDSS + r] = v.x;
            As[(c4 * 4 + 1) * LDSS + r] = v.y;
            As[(c4 * 4 + 2) * LDSS + r] = v.z;
            As[(c4 * 4 + 3) * LDSS + r] = v.w;
        }
        #pragma unroll
        for (int i = 0; i < 2; ++i) {           // B: 16x128 = 512 float4
            const int slot = tid + i * 256;
            const int r = slot >> 5, c4 = slot & 31;
            float4 v = *(const float4*)(Bm + (size_t)(ks + r) * Nn + col0 + c4 * 4);
            *(float4*)&Bs[r * LDSS + c4 * 4] = v;
        }
        __syncthreads();
        #pragma unroll
        for (int k = 0; k < BK; ++k) {
            const float4 a0 = *(const float4*)&As[k * LDSS + ty * 8];
            const float4 a1 = *(const float4*)&As[k * LDSS + ty * 8 + 4];
            const float4 b0 = *(const float4*)&Bs[k * LDSS + tx * 8];
            const float4 b1 = *(const float4*)&Bs[k * LDSS + tx * 8 + 4];
            const float av[8] = {a0.x, a0.y, a0.z, a0.w, a1.x, a1.y, a1.z, a1.w};
            const float bv[8] = {b0.x, b0.y, b0.z, b0.w, b1.x, b1.y, b1.z, b1.w};
            #pragma unroll
            for (int j = 0; j < 8; ++j)
                #pragma unroll
                for (int i = 0; i < 8; ++i)
                    c[j][i] = fmaf(av[j], bv[i], c[j][i]);
        }
        __syncthreads();
    }

    #pragma unroll
    for (int j = 0; j < 8; ++j) {
        const int m = row0 + ty * 8 + j;
        if (m >= M) continue;
        const int crow = (EPI == EPI_SCATTER_ADD) ? scat[m] : m;
        float* cp = C + (size_t)crow * Nn + col0 + tx * 8;
        #pragma unroll
        for (int hf = 0; hf < 2; ++hf) {
            float4 v;
            v.x = c[j][hf * 4 + 0]; v.y = c[j][hf * 4 + 1];
            v.z = c[j][hf * 4 + 2]; v.w = c[j][hf * 4 + 3];
            if (EPI == EPI_BIAS || EPI == EPI_BIAS_GELU || EPI == EPI_ADD_BIAS) {
                const float* bp = bias + col0 + tx * 8 + hf * 4;
                v.x += bp[0]; v.y += bp[1]; v.z += bp[2]; v.w += bp[3];
            }
            if (EPI == EPI_BIAS_GELU) {
                v.x = gelu_f(v.x); v.y = gelu_f(v.y); v.z = gelu_f(v.z); v.w = gelu_f(v.w);
            }
            if (EPI == EPI_ADD || EPI == EPI_ADD_BIAS || EPI == EPI_SCATTER_ADD) {
                const float4 o = *(const float4*)(cp + hf * 4);
                v.x += o.x; v.y += o.y; v.z += o.z; v.w += o.w;
            }
            *(float4*)(cp + hf * 4) = v;
        }
    }
}

// ---------------- RoPE on q,k halves of qkv ----------------
__global__ __launch_bounds__(256) void rope_kernel(float* __restrict__ qkv,
                                                   const int* __restrict__ tk,
                                                   const int* __restrict__ qsi)
{
    const int i = blockIdx.x * 256 + threadIdx.x;   // [t(0..3999)][which(2)][h(8)][p(16)]
    const int p = i & 15;
    const int h = (i >> 4) & 7;
    const int which = (i >> 7) & 1;
    const int t = i >> 8;
    if (t >= NB * KSA) return;
    const int gt = tk[t];
    float ang;
    if (p < 6)       ang = (float)qsi[NQ + gt]     * expf(-(float)p        * 0.7675283643313485f);  // ln(100)/6
    else if (p < 12) ang = (float)qsi[2 * NQ + gt] * expf(-(float)(p - 6)  * 0.7675283643313485f);
    else             ang = (float)qsi[3 * NQ + gt] * expf(-(float)(p - 12) * 0.5756462732485115f);  // ln(10)/4
    const float cs = cosf(ang), sn = sinf(ang);
    float* base = qkv + (size_t)t * 768 + which * 256 + h * 32 + p * 2;
    const float x0 = base[0], x1 = base[1];
    base[0] = x0 * cs - x1 * sn;
    base[1] = x0 * sn + x1 * cs;
}

// ---------------- flash attention over selected tokens ----------------
__global__ __launch_bounds__(256) void attn_kernel(const float* __restrict__ qkv,
                                                   float* __restrict__ attnout)
{
    __shared__ float Klds[64 * 36];
    __shared__ float Vlds[64 * 36];
    const int bid  = blockIdx.x;
    const int tile = bid & 31;           // 32 q-tiles of 32 rows (last partial)
    const int h    = (bid >> 5) & 7;
    const int b    = bid >> 8;
    const int tid  = threadIdx.x;
    const int r = tid >> 3, s = tid & 7;
    const int qg = tile * 32 + r;
    const int qrow = b * KSA + (qg < KSA ? qg : KSA - 1);

    float q[DH];
    {
        const float* qp = qkv + (size_t)qrow * 768 + h * DH;
        #pragma unroll
        for (int i = 0; i < 8; ++i) {
            const float4 v = *(const float4*)(qp + i * 4);
            q[i * 4 + 0] = v.x; q[i * 4 + 1] = v.y; q[i * 4 + 2] = v.z; q[i * 4 + 3] = v.w;
        }
    }
    float acc[DH];
    #pragma unroll
    for (int d = 0; d < DH; ++d) acc[d] = 0.f;
    float m_run = -1e30f, s_run = 0.f;

    for (int kc = 0; kc < KSA; kc += 64) {
        __syncthreads();
        #pragma unroll
        for (int i = 0; i < 2; ++i) {
            const int slot = tid + i * 256;
            const int kr = slot >> 3, c4 = slot & 7;
            const int kg = kc + kr;
            const int krow = b * KSA + (kg < KSA ? kg : KSA - 1);
            const float* kp = qkv + (size_t)krow * 768 + 256 + h * DH + c4 * 4;
            *(float4*)&Klds[kr * 36 + c4 * 4] = *(const float4*)kp;
            *(float4*)&Vlds[kr * 36 + c4 * 4] = *(const float4*)(kp + 256);
        }
        __syncthreads();
        float sc[8];
        #pragma unroll
        for (int j = 0; j < 8; ++j) {
            const int kl = j * 8 + s;                      // lane-s stride 1 row: conflict-free
            const float* kb = &Klds[kl * 36];
            float dot = 0.f;
            #pragma unroll
            for (int d4 = 0; d4 < 8; ++d4) {
                const float4 kv = *(const float4*)(kb + d4 * 4);
                dot = fmaf(q[d4 * 4 + 0], kv.x, dot);
                dot = fmaf(q[d4 * 4 + 1], kv.y, dot);
                dot = fmaf(q[d4 * 4 + 2], kv.z, dot);
                dot = fmaf(q[d4 * 4 + 3], kv.w, dot);
            }
            sc[j] = (kc + kl < KSA) ? dot * SCALE : -1e30f;
        }
        float mx = sc[0];
        #pragma unroll
        for (int j = 1; j < 8; ++j) mx = fmaxf(mx, sc[j]);
        mx = fmaxf(mx, __shfl_xor(mx, 1));
        mx = fmaxf(mx, __shfl_xor(mx, 2));
        mx = fmaxf(mx, __shfl_xor(mx, 4));
        const float newm = fmaxf(m_run, mx);
        const float fac = expf(m_run - newm);
        m_run = newm;
        s_run *= fac;
        #pragma unroll
        for (int d = 0; d < DH; ++d) acc[d] *= fac;
        float p[8];
        #pragma unroll
        for (int j = 0; j < 8; ++j) { p[j] = expf(sc[j] - m_run); s_run += p[j]; }
        #pragma unroll
        for (int j = 0; j < 8; ++j) {
            const float* vb = &Vlds[(j * 8 + s) * 36];
            #pragma unroll
            for (int d4 = 0; d4 < 8; ++d4) {
                const float4 vv = *(const float4*)(vb + d4 * 4);
                acc[d4 * 4 + 0] = fmaf(p[j], vv.x, acc[d4 * 4 + 0]);
                acc[d4 * 4 + 1] = fmaf(p[j], vv.y, acc[d4 * 4 + 1]);
                acc[d4 * 4 + 2] = fmaf(p[j], vv.z, acc[d4 * 4 + 2]);
                acc[d4 * 4 + 3] = fmaf(p[j], vv.w, acc[d4 * 4 + 3]);
            }
        }
    }
    #pragma unroll
    for (int d = 0; d < DH; ++d) {
        float v = acc[d];
        v += __shfl_xor(v, 1); v += __shfl_xor(v, 2); v += __shfl_xor(v, 4);
        acc[d] = v;
    }
    s_run += __shfl_xor(s_run, 1);
    s_run += __shfl_xor(s_run, 2);
    s_run += __shfl_xor(s_run, 4);
    if (qg < KSA) {
        const float inv = 1.0f / s_run;
        float4 o = make_float4(0.f, 0.f, 0.f, 0.f);
        #pragma unroll
        for (int d4 = 0; d4 < 8; ++d4) {        // static-index select of this lane's 4 dims
            if (s == d4) {
                o.x = acc[d4 * 4 + 0] * inv; o.y = acc[d4 * 4 + 1] * inv;
                o.z = acc[d4 * 4 + 2] * inv; o.w = acc[d4 * 4 + 3] * inv;
            }
        }
        *(float4*)(attnout + (size_t)(b * KSA + qg) * D + h * DH + s * 4) = o;
    }
}

// ---------------- softmax over 16 sampling weights per (n,h) ----------------
__global__ __launch_bounds__(256) void softmax16_kernel(float* __restrict__ aw)
{
    const int g = blockIdx.x * 256 + threadIdx.x;   // (n*8+h), exact grid
    float* p = aw + (size_t)g * 16;
    float v[16];
    float mx = -1e30f;
    #pragma unroll
    for (int i = 0; i < 16; ++i) { v[i] = p[i]; mx = fmaxf(mx, v[i]); }
    float s = 0.f;
    #pragma unroll
    for (int i = 0; i < 16; ++i) { v[i] = expf(v[i] - mx); s += v[i]; }
    const float inv = 1.0f / s;
    #pragma unroll
    for (int i = 0; i < 16; ++i) p[i] = v[i] * inv;
}

// ---------------- multi-scale deformable sampling ----------------
__global__ __launch_bounds__(256) void msdeform_kernel(const float* __restrict__ val,
                                                       const float* __restrict__ offb,
                                                       const float* __restrict__ awb,
                                                       const int* __restrict__ qsi,
                                                       const int* __restrict__ shp,
                                                       float* __restrict__ msd)
{
    const int n = blockIdx.x;
    const int tid = threadIdx.x;
    const int h = tid >> 5, d = tid & 31;
    const int b = n / PER;
    const int iy = qsi[NQ + n], ix = qsi[2 * NQ + n], lvl = qsi[3 * NQ + n];
    int Hs[4], Ws[4], LS[4];
    int accu = 0;
    #pragma unroll
    for (int l = 0; l < 4; ++l) { Hs[l] = shp[2 * l]; Ws[l] = shp[2 * l + 1]; LS[l] = accu; accu += Hs[l] * Ws[l]; }
    float refy = 0.f, refx = 0.f;
    #pragma unroll
    for (int l = 0; l < 4; ++l) {
        if (lvl == l) { refy = ((float)iy + 0.5f) / (float)Hs[l]; refx = ((float)ix + 0.5f) / (float)Ws[l]; }
    }
    // offsets layout: (N, H, L, NPTS, 2) -> head stride = L*NPTS*2 = 32  (was h*64: BUG, fixed)
    const float* offn = offb + (size_t)n * 256 + h * 32;
    const float* awn  = awb + (size_t)n * 128 + h * 16;
    const float* valb = val + (size_t)b * STOT * D + h * DH + d;
    float acc = 0.f;
    #pragma unroll
    for (int l = 0; l < 4; ++l) {
        const float Hl = (float)Hs[l], Wl = (float)Ws[l];
        const int Wi = Ws[l], ls = LS[l];
        #pragma unroll
        for (int p = 0; p < 4; ++p) {
            const float oy = offn[l * 8 + p * 2], ox = offn[l * 8 + p * 2 + 1];
            const float locy = refy + oy / Hl, locx = refx + ox / Wl;
            const float py = locy * Hl - 0.5f, px = locx * Wl - 0.5f;
            const float y0 = floorf(py), x0 = floorf(px);
            const float wy = py - y0, wx = px - x0;
            const float a = awn[l * 4 + p];
            #pragma unroll
            for (int t = 0; t < 4; ++t) {
                const int dy = t >> 1, dxs = t & 1;
                const float yy = y0 + (float)dy, xx = x0 + (float)dxs;
                const bool inb = (yy >= 0.f) && (yy < Hl) && (xx >= 0.f) && (xx < Wl);
                const float w = (dy ? wy : 1.f - wy) * (dxs ? wx : 1.f - wx);
                const float yc = fminf(fmaxf(yy, 0.f), Hl - 1.f);
                const float xc = fminf(fmaxf(xx, 0.f), Wl - 1.f);
                const int flat = ls + (int)yc * Wi + (int)xc;
                const float g = valb[(size_t)flat * D];
                acc = fmaf(a * w * (inb ? 1.f : 0.f), g, acc);
            }
        }
    }
    msd[(size_t)n * D + h * DH + d] = acc;
}

// ---------------- host-side launch ----------------
extern "C" void kernel_launch(void* const* d_in, const int* in_sizes, int n_in,
                              void* d_out, int out_size, void* d_ws, size_t ws_size,
                              hipStream_t stream)
{
    const float* queries = (const float*)d_in[0];
    const float* sal     = (const float*)d_in[2];
    const int*   qsi     = (const int*)d_in[3];
    const float* fmaps   = (const float*)d_in[4];
    const int*   shp     = (const int*)d_in[5];
    const float* elec    = (const float*)d_in[6];
    const float* w_qkv   = (const float*)d_in[7];
    const float* w_out   = (const float*)d_in[8];
    const float* ln1g    = (const float*)d_in[9];
    const float* ln1b    = (const float*)d_in[10];
    const float* w_value = (const float*)d_in[11];
    const float* w_off   = (const float*)d_in[12];
    const float* b_off   = (const float*)d_in[13];
    const float* w_aw    = (const float*)d_in[14];
    const float* b_aw    = (const float*)d_in[15];
    const float* w_out2  = (const float*)d_in[16];
    const float* ln2g    = (const float*)d_in[17];
    const float* ln2b    = (const float*)d_in[18];
    const float* w1      = (const float*)d_in[19];
    const float* b1      = (const float*)d_in[20];
    const float* w2      = (const float*)d_in[21];
    const float* b2      = (const float*)d_in[22];
    const float* ln3g    = (const float*)d_in[23];
    const float* ln3b    = (const float*)d_in[24];
    float* outq = (float*)d_out;
    (void)ws_size; (void)in_sizes; (void)n_in; (void)out_size;

    // ---- workspace layout: phases overlap in one pool (peak ~94 MB) ----
    char* base = (char*)d_ws;
    int*   tk   = (int*)base;                                   //    16,384 B (padded)
    float* xn2  = (float*)(base + 16384);                       // 20,480,000 B (phases B+C)
    char*  pool = base + 16384 + 20480000;
    // phase A (self-attention scratch)
    float* xn1   = (float*)pool;                                //  4,096,000
    float* qkvb  = (float*)(pool + 4096000);                    // 12,288,000
    float* attno = (float*)(pool + 4096000 + 12288000);         //  4,096,000
    // phase B (deformable scratch) — aliases phase A
    float* offb  = (float*)pool;                                // 20,480,000
    float* awb   = (float*)(pool + 20480000);                   // 10,240,000
    float* valb  = (float*)(pool + 30720000);                   // 22,282,240
    float* msd   = (float*)(pool + 53002240);                   // 20,480,000
    // phase C (FFN scratch) — aliases phases A/B
    float* hid   = (float*)pool;                                // 40,960,000

    // queries -> out (working buffer, updated in place)
    hipMemcpyAsync(outq, queries, (size_t)NQ * D * 4, hipMemcpyDeviceToDevice, stream);

    topk_kernel<<<NB, 1024, 0, stream>>>(elec, sal, tk);

    // ---- self-attention over selected tokens ----
    ln_kernel<true><<<1000, 256, 0, stream>>>(queries, ln1g, ln1b, xn1, NB * KSA, tk);
    gemm_f32<EPI_STORE><<<dim3(6, 32), 256, 0, stream>>>(xn1, w_qkv, nullptr, qkvb, nullptr, NB * KSA, 768, D);
    rope_kernel<<<4000, 256, 0, stream>>>(qkvb, tk, qsi);
    attn_kernel<<<NB * NH * 32, 256, 0, stream>>>(qkvb, attno);
    gemm_f32<EPI_SCATTER_ADD><<<dim3(2, 32), 256, 0, stream>>>(attno, w_out, nullptr, outq, tk, NB * KSA, D, D);

    // ---- deformable attention over all tokens ----
    ln_kernel<false><<<5000, 256, 0, stream>>>(outq, ln2g, ln2b, xn2, NQ, nullptr);
    gemm_f32<EPI_BIAS><<<dim3(2, 157), 256, 0, stream>>>(xn2, w_off, b_off, offb, nullptr, NQ, 256, D);
    gemm_f32<EPI_BIAS><<<dim3(1, 157), 256, 0, stream>>>(xn2, w_aw, b_aw, awb, nullptr, NQ, 128, D);
    softmax16_kernel<<<625, 256, 0, stream>>>(awb);
    gemm_f32<EPI_STORE><<<dim3(2, 170), 256, 0, stream>>>(fmaps, w_value, nullptr, valb, nullptr, NB * STOT, 256, D);
    msdeform_kernel<<<NQ, 256, 0, stream>>>(valb, offb, awb, qsi, shp, msd);
    gemm_f32<EPI_ADD><<<dim3(2, 157), 256, 0, stream>>>(msd, w_out2, nullptr, outq, nullptr, NQ, 256, D);

    // ---- FFN (two row-halves to bound workspace) ----
    ln_kernel<false><<<5000, 256, 0, stream>>>(outq, ln3g, ln3b, xn2, NQ, nullptr);
    for (int half = 0; half < 2; ++half) {
        const float* a = xn2 + (size_t)half * (NQ / 2) * D;
        float* o = outq + (size_t)half * (NQ / 2) * D;
        gemm_f32<EPI_BIAS_GELU><<<dim3(8, 79), 256, 0, stream>>>(a, w1, b1, hid, nullptr, NQ / 2, DFF, D);
        gemm_f32<EPI_ADD_BIAS><<<dim3(2, 79), 256, 0, stream>>>(hid, w2, b2, o, nullptr, NQ / 2, 256, DFF);
    }
}